// Round 6
// baseline (1025.673 us; speedup 1.0000x reference)
//
#include <hip/hip_runtime.h>
#include <math.h>

typedef __bf16 bf16x8 __attribute__((ext_vector_type(8)));
typedef float f32x4 __attribute__((ext_vector_type(4)));
typedef float float4v __attribute__((ext_vector_type(4)));

#define TWO_PI_F 6.28318530717958647692f
#define INV_4PI_F 0.079577471545947667884f

// packed-weight layout offsets in __bf16 elements inside d_ws
#define W1F_OFF 0
#define W1B_OFF 524288
#define W2F_OFF 1048576
#define W2B_OFF 1114112
#define W3F_OFF 1179648
#define W3B_OFF 1245184
#define W4F_OFF 1310720
#define W4B_OFF 1376256

// async 16B/lane global->LDS: dest = wave-uniform lds base + lane*16
__device__ __forceinline__ void async16(void* lds, const void* g) {
  __builtin_amdgcn_global_load_lds(
      (const __attribute__((address_space(1))) void*)g,
      (__attribute__((address_space(3))) void*)lds, 16, 0, 0);
}

// ---------------------------------------------------------------------------
// k_pack: coalesced LDS-transpose pack of fp32 weights into bf16 MFMA
// B-operand tile order (layout proven rounds 1-5).
// Fwd (H@W):  B[k][n] = W[k][n].  Bwd (G@W^T): B[k][n] = W[n][k].
// N=256 chunk: c = ((kc*16+ct)*4+q)*16+n holds B[kc*32+q*8+j][ct*16+n].
// W1B (N=2048): c = ((ct*8+kc)*4+q)*16+n (ct-major: one ct block = 8KB).
// ---------------------------------------------------------------------------
__global__ void k_pack(const float* __restrict__ W1, const float* __restrict__ W2,
                       const float* __restrict__ W3, const float* __restrict__ W4,
                       __bf16* __restrict__ ws) {
  __shared__ __bf16 T[32 * 264];
  int b = blockIdx.x, t = threadIdx.x;
  const float* W; long base; int kc, nb; bool bwd, w1b = false;
  if (b < 64)       { W = W1; bwd = false; base = W1F_OFF; kc = b;       nb = 0; }
  else if (b < 72)  { W = W2; bwd = false; base = W2F_OFF; kc = b - 64;  nb = 0; }
  else if (b < 80)  { W = W3; bwd = false; base = W3F_OFF; kc = b - 72;  nb = 0; }
  else if (b < 88)  { W = W4; bwd = false; base = W4F_OFF; kc = b - 80;  nb = 0; }
  else if (b < 152) { W = W1; bwd = true;  base = W1B_OFF; kc = (b - 88) & 7; nb = (b - 88) >> 3; w1b = true; }
  else if (b < 160) { W = W2; bwd = true;  base = W2B_OFF; kc = b - 152; nb = 0; }
  else if (b < 168) { W = W3; bwd = true;  base = W3B_OFF; kc = b - 160; nb = 0; }
  else              { W = W4; bwd = true;  base = W4B_OFF; kc = b - 168; nb = 0; }

  if (!bwd) {
    #pragma unroll
    for (int i = 0; i < 8; ++i) {
      int idx = t + i * 256;
      int k = idx >> 6;
      int n4 = (idx & 63) * 4;
      float4v v = *(const float4v*)(W + (size_t)(kc * 32 + k) * 256 + n4);
      #pragma unroll
      for (int j = 0; j < 4; ++j) T[k * 264 + n4 + j] = (__bf16)v[j];
    }
  } else {
    #pragma unroll
    for (int i = 0; i < 8; ++i) {
      int idx = t + i * 256;
      int n = idx >> 3;
      int k4 = (idx & 7) * 4;
      float4v v = *(const float4v*)(W + (size_t)(nb * 256 + n) * 256 + kc * 32 + k4);
      #pragma unroll
      for (int j = 0; j < 4; ++j) T[(k4 + j) * 264 + n] = (__bf16)v[j];
    }
  }
  __syncthreads();
  int ctl = t >> 4, n = t & 15;
  #pragma unroll
  for (int q = 0; q < 4; ++q) {
    bf16x8 v;
    #pragma unroll
    for (int j = 0; j < 8; ++j) v[j] = T[(q * 8 + j) * 264 + ctl * 16 + n];
    long c;
    if (w1b) c = (((long)(nb * 16 + ctl) * 8 + kc) * 4 + q) * 16 + n;
    else     c = (((long)kc * 16 + ctl) * 4 + q) * 16 + n;
    *(bf16x8*)(ws + base + c * 8) = v;
  }
}

// ---------------------------------------------------------------------------
// Biot-Savart: 2 threads/point, seg/mid precomputed once per block in LDS.
// out layout: f[N] | current[3N] | df[3N] | alpha[3N]
// ---------------------------------------------------------------------------
__global__ void k_biot(const float* __restrict__ x, const float* __restrict__ bdry,
                       float* __restrict__ out, int N, int M) {
  __shared__ float4v em[512 * 2];
  int tid = threadIdx.x;
  for (int s = tid; s < M; s += 256) {
    int sn = (s + 1 == M) ? 0 : s + 1;
    float b0 = bdry[s * 3], b1 = bdry[s * 3 + 1], b2 = bdry[s * 3 + 2];
    float c0 = bdry[sn * 3], c1 = bdry[sn * 3 + 1], c2 = bdry[sn * 3 + 2];
    float4v a = {c0 - b0, c1 - b1, c2 - b2, 0.5f * (c0 + b0)};
    float4v bv = {0.5f * (c1 + b1), 0.5f * (c2 + b2), 0.f, 0.f};
    em[s * 2] = a; em[s * 2 + 1] = bv;
  }
  __syncthreads();
  int idx = blockIdx.x * 128 + (tid >> 1);
  int half = tid & 1;
  if (idx >= N) return;
  float x0 = fminf(fmaxf(x[idx * 3 + 0], -1.f), 1.f);
  float x1 = fminf(fmaxf(x[idx * 3 + 1], -1.f), 1.f);
  float x2 = fminf(fmaxf(x[idx * 3 + 2], -1.f), 1.f);
  float a0 = 0.f, a1 = 0.f, a2 = 0.f;
  int s0i = half * (M / 2), s1i = s0i + M / 2;
  for (int s = s0i; s < s1i; ++s) {
    float4v eA = em[s * 2], eB = em[s * 2 + 1];
    float d0 = x0 - eA[3], d1 = x1 - eB[0], d2 = x2 - eB[1];
    float r2 = d0 * d0 + d1 * d1 + d2 * d2;
    float inv = rsqrtf(r2);
    float inv3 = inv * inv * inv;
    float n0 = eA[1] * d2 - eA[2] * d1;
    float n1 = eA[2] * d0 - eA[0] * d2;
    float n2 = eA[0] * d1 - eA[1] * d0;
    a0 = fmaf(n0, inv3, a0); a1 = fmaf(n1, inv3, a1); a2 = fmaf(n2, inv3, a2);
  }
  a0 += __shfl_xor(a0, 1, 64);
  a1 += __shfl_xor(a1, 1, 64);
  a2 += __shfl_xor(a2, 1, 64);
  if (!half) {
    float* alpha = out + (size_t)7 * N;
    alpha[idx * 3 + 0] = a0 * INV_4PI_F;
    alpha[idx * 3 + 1] = a1 * INV_4PI_F;
    alpha[idx * 3 + 2] = a2 * INV_4PI_F;
  }
}

// ---------------------------------------------------------------------------
// Fused MLP fwd+bwd. Col-split: 256 thr = 4 waves, 64 rows/block; wave owns a
// 64-col slice of all 64 rows (acc = 4mt x 4nt f32x4 = 64 regs, round-3-proven
// budget). Activations in ONE LDS buffer in FRAG-MAJOR layout
// sA[mt][kc][quad][ml][8] -> all A-reads are lane-contiguous 1KB, 0 conflicts.
// B staged via global_load_lds dbuf (16KB chunks); each wave reads only its
// 64-col slice -> B LDS-reads 1.8 MB/block (vs 11.6 row-split).
// sigma (softplus') packed per-lane in bf16x8[8] per layer (32 VGPR/layer).
// ---------------------------------------------------------------------------
__launch_bounds__(256, 2)
__global__ void k_mlp(const float* __restrict__ x, const float* __restrict__ Brff,
                      const float* __restrict__ b1, const float* __restrict__ b2,
                      const float* __restrict__ b3, const float* __restrict__ b4,
                      const float* __restrict__ W5, const float* __restrict__ b5,
                      const __bf16* __restrict__ wsw, float* __restrict__ out, int N) {
  __shared__ __attribute__((aligned(16))) __bf16 sA[16384];     // 32 KB acts, frag-major
  __shared__ __attribute__((aligned(16))) __bf16 sW[2 * 8192];  // 32 KB B dbuf
  __shared__ float sX[192];                                     // 64 rows x 3
  __shared__ float sRed[768];                                   // cross-wave reductions

  const int tid  = threadIdx.x;
  const int wave = tid >> 6;
  const int lane = tid & 63;
  const int ml   = lane & 15;
  const int quad = lane >> 4;
  const int rowblk = blockIdx.x * 64;

  if (tid < 192) {
    float v = x[(size_t)rowblk * 3 + tid];
    sX[tid] = fminf(fmaxf(v, -1.f), 1.f);
  }
  __syncthreads();

  f32x4 acc[4][4];
  bf16x8 sg1[8], sg2[8], sg3[8];   // sigma: vec = mt*2+(nt>>1), elem = (nt&1)*4+r
  int cur = 0;

  auto issue_chunk = [&](int buf, const __bf16* src) {
    const char* s = (const char*)src;
    char* dbase = (char*)sW + buf * 16384;
    #pragma unroll
    for (int r = 0; r < 4; ++r) {
      int off = (r * 256 + wave * 64) * 16;     // wave-uniform
      async16(dbase + off, s + off + lane * 16);
    }
  };
  auto zacc = [&]() {
    #pragma unroll
    for (int mt = 0; mt < 4; ++mt)
      #pragma unroll
      for (int nt = 0; nt < 4; ++nt) { f32x4 z = {0.f,0.f,0.f,0.f}; acc[mt][nt] = z; }
  };

  // epilogue dest offsets (frag-major): elem = mt*4096 + soff[nt] + (quad*4+r)*8
  int soff[4];
  #pragma unroll
  for (int nt = 0; nt < 4; ++nt) {
    int t = nt * 16 + ml;
    soff[nt] = (wave * 2 + (t >> 5)) * 512 + ((t >> 3) & 3) * 128 + (t & 7);
  }

  // ---- Forward layer 1: y(RFF) @ W1, K=2048 = 8 chunks of K=256 ----
  const int yrow = tid >> 2;          // 0..63
  const int ymt  = yrow >> 4;
  const int ymp  = yrow & 15;
  const int ykc0 = (tid & 3) * 2;     // first of two kc blocks (K=32 each)
  const float ya0 = sX[yrow * 3], ya1 = sX[yrow * 3 + 1], ya2 = sX[yrow * 3 + 2];

  zacc();
  issue_chunk(0, wsw + W1F_OFF);
  for (int kc8 = 0; kc8 < 8; ++kc8) {
    __syncthreads();                  // all waves done reading sA (prev chunk)
    bool isSin = (kc8 < 4);
    #pragma unroll
    for (int h = 0; h < 2; ++h) {
      int kc = ykc0 + h;
      #pragma unroll
      for (int qp = 0; qp < 4; ++qp) {
        int cb = (kc8 & 3) * 256 + kc * 32 + qp * 8;
        float4v b0a = *(const float4v*)(Brff + cb),        b0b = *(const float4v*)(Brff + cb + 4);
        float4v b1a = *(const float4v*)(Brff + 1024 + cb), b1b = *(const float4v*)(Brff + 1028 + cb);
        float4v b2a = *(const float4v*)(Brff + 2048 + cb), b2b = *(const float4v*)(Brff + 2052 + cb);
        bf16x8 yv;
        #pragma unroll
        for (int j = 0; j < 4; ++j) {
          float t = __builtin_amdgcn_fractf(ya0 * b0a[j] + ya1 * b1a[j] + ya2 * b2a[j]);
          yv[j] = (__bf16)(isSin ? __builtin_amdgcn_sinf(t) : __builtin_amdgcn_cosf(t));
        }
        #pragma unroll
        for (int j = 0; j < 4; ++j) {
          float t = __builtin_amdgcn_fractf(ya0 * b0b[j] + ya1 * b1b[j] + ya2 * b2b[j]);
          yv[j + 4] = (__bf16)(isSin ? __builtin_amdgcn_sinf(t) : __builtin_amdgcn_cosf(t));
        }
        *(bf16x8*)(sA + ymt * 4096 + ((kc * 4 + qp) * 16 + ymp) * 8) = yv;
      }
    }
    #pragma unroll 1
    for (int c = 0; c < 8; ++c) {
      int g = kc8 * 8 + c;
      __syncthreads();                // chunk g staged; y-chunk visible (c==0)
      issue_chunk(cur ^ 1, (g + 1 < 64) ? wsw + W1F_OFF + (size_t)(g + 1) * 8192
                                        : wsw + W2F_OFF);
      const __bf16* wb = sW + cur * 8192;
      bf16x8 af[4];
      #pragma unroll
      for (int mt = 0; mt < 4; ++mt)
        af[mt] = *(const bf16x8*)(sA + mt * 4096 + ((c * 4 + quad) * 16 + ml) * 8);
      #pragma unroll
      for (int nt = 0; nt < 4; ++nt) {
        bf16x8 bfr = *(const bf16x8*)(wb + (wave * 4 + nt) * 512 + quad * 128 + ml * 8);
        #pragma unroll
        for (int mt = 0; mt < 4; ++mt)
          acc[mt][nt] = __builtin_amdgcn_mfma_f32_16x16x32_bf16(af[mt], bfr, acc[mt][nt], 0, 0, 0);
      }
      cur ^= 1;
    }
  }

  // K=256,N=256 GEMM from sA (frag-major) x staged B chunks
  auto gemm = [&](long woff, long nextoff) {
    zacc();
    #pragma unroll 1
    for (int c = 0; c < 8; ++c) {
      __syncthreads();
      issue_chunk(cur ^ 1, wsw + ((c + 1 < 8) ? woff + (size_t)(c + 1) * 8192 : nextoff));
      const __bf16* wb = sW + cur * 8192;
      bf16x8 af[4];
      #pragma unroll
      for (int mt = 0; mt < 4; ++mt)
        af[mt] = *(const bf16x8*)(sA + mt * 4096 + ((c * 4 + quad) * 16 + ml) * 8);
      #pragma unroll
      for (int nt = 0; nt < 4; ++nt) {
        bf16x8 bfr = *(const bf16x8*)(wb + (wave * 4 + nt) * 512 + quad * 128 + ml * 8);
        #pragma unroll
        for (int mt = 0; mt < 4; ++mt)
          acc[mt][nt] = __builtin_amdgcn_mfma_f32_16x16x32_bf16(af[mt], bfr, acc[mt][nt], 0, 0, 0);
      }
      cur ^= 1;
    }
  };

  // softplus epilogue: h -> sA (frag-major, in place), sigma -> packed regs
  auto epi_h = [&](const float* __restrict__ bias, bf16x8* sg) {
    __syncthreads();                  // all waves done reading sA
    float bc[4];
    #pragma unroll
    for (int nt = 0; nt < 4; ++nt) bc[nt] = bias[wave * 64 + nt * 16 + ml];
    #pragma unroll
    for (int mt = 0; mt < 4; ++mt)
      #pragma unroll
      for (int nt = 0; nt < 4; ++nt)
        #pragma unroll
        for (int r = 0; r < 4; ++r) {
          float z = acc[mt][nt][r] + bc[nt];
          float ez = __expf(-fabsf(z));
          float sp = fmaxf(z, 0.f) + __logf(1.f + ez);
          float sv = (z >= 0.f) ? 1.f / (1.f + ez) : ez / (1.f + ez);
          sg[mt * 2 + (nt >> 1)][(nt & 1) * 4 + r] = (__bf16)sv;
          sA[mt * 4096 + soff[nt] + (quad * 4 + r) * 8] = (__bf16)sp;
        }
    __syncthreads();
  };

  // backward gate epilogue: g = acc * sigma -> sA (in place)
  auto epi_g = [&](const bf16x8* sg) {
    __syncthreads();
    #pragma unroll
    for (int mt = 0; mt < 4; ++mt)
      #pragma unroll
      for (int nt = 0; nt < 4; ++nt)
        #pragma unroll
        for (int r = 0; r < 4; ++r) {
          float g = acc[mt][nt][r] * (float)sg[mt * 2 + (nt >> 1)][(nt & 1) * 4 + r];
          sA[mt * 4096 + soff[nt] + (quad * 4 + r) * 8] = (__bf16)g;
        }
    __syncthreads();
  };

  // ---- Forward ----
  epi_h(b1, sg1);
  gemm(W2F_OFF, W3F_OFF); epi_h(b2, sg2);
  gemm(W3F_OFF, W4F_OFF); epi_h(b3, sg3);
  gemm(W4F_OFF, W4B_OFF);

  // ---- Layer-4 epilogue: f head + g4 = sigma(z4)*W5 -> sA ----
  {
    __syncthreads();
    float bc[4], w5c[4];
    #pragma unroll
    for (int nt = 0; nt < 4; ++nt) {
      int col = wave * 64 + nt * 16 + ml;
      bc[nt] = b4[col]; w5c[nt] = W5[col];
    }
    float fp[16];
    #pragma unroll
    for (int i = 0; i < 16; ++i) fp[i] = 0.f;
    #pragma unroll
    for (int mt = 0; mt < 4; ++mt)
      #pragma unroll
      for (int nt = 0; nt < 4; ++nt)
        #pragma unroll
        for (int r = 0; r < 4; ++r) {
          float z = acc[mt][nt][r] + bc[nt];
          float ez = __expf(-fabsf(z));
          float sp = fmaxf(z, 0.f) + __logf(1.f + ez);
          float sv = (z >= 0.f) ? 1.f / (1.f + ez) : ez / (1.f + ez);
          fp[mt * 4 + r] += sp * w5c[nt];
          sA[mt * 4096 + soff[nt] + (quad * 4 + r) * 8] = (__bf16)(sv * w5c[nt]);
        }
    #pragma unroll
    for (int i = 0; i < 16; ++i) {
      float v = fp[i];
      #pragma unroll
      for (int m = 1; m < 16; m <<= 1) v += __shfl_xor(v, m, 64);
      fp[i] = v;
    }
    if (ml == 0) {
      #pragma unroll
      for (int mt = 0; mt < 4; ++mt)
        #pragma unroll
        for (int r = 0; r < 4; ++r)
          sRed[wave * 64 + mt * 16 + quad * 4 + r] = fp[mt * 4 + r];
    }
    __syncthreads();
    if (tid < 64)
      out[rowblk + tid] = sRed[tid] + sRed[64 + tid] + sRed[128 + tid] + sRed[192 + tid] + b5[0];
  }

  // ---- Backward through W4, W3, W2 ----
  gemm(W4B_OFF, W3B_OFF); epi_g(sg3);
  gemm(W3B_OFF, W2B_OFF); epi_g(sg2);
  gemm(W2B_OFF, W2B_OFF); epi_g(sg1);   // dummy prefetch, never consumed

  // ---- Backward L1: dy = g1 @ W1^T fused with dproj & dx. Wave owns pair-cols
  //      [wave*256, wave*256+256); p-pairs share the g1 A-frag reads. B (W1B)
  //      read straight from global (L2-resident 1 MB). ----
  {
    float dxa[16][3];
    #pragma unroll
    for (int i = 0; i < 16; ++i) { dxa[i][0] = 0.f; dxa[i][1] = 0.f; dxa[i][2] = 0.f; }

    for (int pp = 0; pp < 8; ++pp) {
      int p0 = pp * 2;
      const __bf16* w0 = wsw + W1B_OFF + (size_t)(wave * 16 + p0) * 4096 + quad * 128 + ml * 8;
      f32x4 aA0[4], aB0[4], aA1[4], aB1[4];
      #pragma unroll
      for (int mt = 0; mt < 4; ++mt) {
        f32x4 z = {0.f,0.f,0.f,0.f};
        aA0[mt] = z; aB0[mt] = z; aA1[mt] = z; aB1[mt] = z;
      }
      #pragma unroll
      for (int kc = 0; kc < 8; ++kc) {
        bf16x8 af[4];
        #pragma unroll
        for (int mt = 0; mt < 4; ++mt)
          af[mt] = *(const bf16x8*)(sA + mt * 4096 + ((kc * 4 + quad) * 16 + ml) * 8);
        bf16x8 bA0 = *(const bf16x8*)(w0 + kc * 512);
        bf16x8 bA1 = *(const bf16x8*)(w0 + 4096 + kc * 512);
        bf16x8 bB0 = *(const bf16x8*)(w0 + 262144 + kc * 512);
        bf16x8 bB1 = *(const bf16x8*)(w0 + 266240 + kc * 512);
        #pragma unroll
        for (int mt = 0; mt < 4; ++mt) {
          aA0[mt] = __builtin_amdgcn_mfma_f32_16x16x32_bf16(af[mt], bA0, aA0[mt], 0, 0, 0);
          aA1[mt] = __builtin_amdgcn_mfma_f32_16x16x32_bf16(af[mt], bA1, aA1[mt], 0, 0, 0);
          aB0[mt] = __builtin_amdgcn_mfma_f32_16x16x32_bf16(af[mt], bB0, aB0[mt], 0, 0, 0);
          aB1[mt] = __builtin_amdgcn_mfma_f32_16x16x32_bf16(af[mt], bB1, aB1[mt], 0, 0, 0);
        }
      }
      #pragma unroll
      for (int pi = 0; pi < 2; ++pi) {
        int c = wave * 256 + (p0 + pi) * 16 + ml;
        float B0 = Brff[c], B1 = Brff[1024 + c], B2 = Brff[2048 + c];
        #pragma unroll
        for (int mt = 0; mt < 4; ++mt)
          #pragma unroll
          for (int r = 0; r < 4; ++r) {
            int row = mt * 16 + quad * 4 + r;
            float t = __builtin_amdgcn_fractf(
                sX[row * 3] * B0 + sX[row * 3 + 1] * B1 + sX[row * 3 + 2] * B2);
            float sn = __builtin_amdgcn_sinf(t);
            float cs = __builtin_amdgcn_cosf(t);
            float dyA = pi ? aA1[mt][r] : aA0[mt][r];
            float dyB = pi ? aB1[mt][r] : aB0[mt][r];
            float dp = dyA * cs - dyB * sn;
            dxa[mt * 4 + r][0] = fmaf(dp, B0, dxa[mt * 4 + r][0]);
            dxa[mt * 4 + r][1] = fmaf(dp, B1, dxa[mt * 4 + r][1]);
            dxa[mt * 4 + r][2] = fmaf(dp, B2, dxa[mt * 4 + r][2]);
          }
      }
    }

    // reduce over ml lanes (cols), then across waves via LDS
    #pragma unroll
    for (int i = 0; i < 16; ++i)
      #pragma unroll
      for (int k = 0; k < 3; ++k) {
        float v = dxa[i][k];
        #pragma unroll
        for (int m = 1; m < 16; m <<= 1) v += __shfl_xor(v, m, 64);
        dxa[i][k] = v;
      }
    if (ml == 0) {
      #pragma unroll
      for (int mt = 0; mt < 4; ++mt)
        #pragma unroll
        for (int r = 0; r < 4; ++r) {
          int row = mt * 16 + quad * 4 + r;
          sRed[wave * 192 + row * 3 + 0] = dxa[mt * 4 + r][0];
          sRed[wave * 192 + row * 3 + 1] = dxa[mt * 4 + r][1];
          sRed[wave * 192 + row * 3 + 2] = dxa[mt * 4 + r][2];
        }
    }
    __syncthreads();
    if (tid < 192) {
      float v = (sRed[tid] + sRed[192 + tid] + sRed[384 + tid] + sRed[576 + tid]) * TWO_PI_F;
      size_t gi = (size_t)rowblk * 3 + tid;
      out[(size_t)4 * N + gi] = v;                              // df
      out[(size_t)N + gi] = v + out[(size_t)7 * N + gi];        // current = df + alpha
    }
  }
}

extern "C" void kernel_launch(void* const* d_in, const int* in_sizes, int n_in,
                              void* d_out, int out_size, void* d_ws, size_t ws_size,
                              hipStream_t stream) {
  const float* x    = (const float*)d_in[0];
  const float* bdry = (const float*)d_in[1];
  const float* Brff = (const float*)d_in[2];
  const float* W1   = (const float*)d_in[3];
  const float* b1   = (const float*)d_in[4];
  const float* W2   = (const float*)d_in[5];
  const float* b2   = (const float*)d_in[6];
  const float* W3   = (const float*)d_in[7];
  const float* b3   = (const float*)d_in[8];
  const float* W4   = (const float*)d_in[9];
  const float* b4   = (const float*)d_in[10];
  const float* W5   = (const float*)d_in[11];
  const float* b5   = (const float*)d_in[12];
  float* out = (float*)d_out;
  __bf16* ws = (__bf16*)d_ws;
  int N = in_sizes[0] / 3;   // 65536
  int M = in_sizes[1] / 3;   // 512

  k_pack<<<176, 256, 0, stream>>>(W1, W2, W3, W4, ws);
  k_biot<<<(N + 127) / 128, 256, 0, stream>>>(x, bdry, out, N, M);
  k_mlp<<<N / 64, 256, 0, stream>>>(x, Brff, b1, b2, b3, b4, W5, b5, ws, out, N);
}